// Round 4
// baseline (5404.544 us; speedup 1.0000x reference)
//
#include <hip/hip_runtime.h>
#include <hip/hip_cooperative_groups.h>

namespace cg = cooperative_groups;

// Match numpy's rounding exactly: no FMA contraction, same op order as reference.
#pragma clang fp contract(off)

#define B_    4
#define NT_   256
#define NZ_   192
#define NX_   192
#define NREC_ 128
#define DT_   0.001f
#define DH_   10.0f

#define N_CELL  (NZ_ * NX_)        // 36864
#define N_FIELD (B_ * N_CELL)      // 147456

#define ROWS   12                  // rows owned per block
#define TILES  (NZ_ / ROWS)        // 16 blocks per batch
#define NBLK   (B_ * TILES)        // 64 blocks total

extern "C" __global__ void __launch_bounds__(256)
wave_persistent(const float* __restrict__ vp, const float* __restrict__ vs,
                const float* __restrict__ rho, const float* __restrict__ wav,
                const int* __restrict__ src_loc, const int* __restrict__ rec_loc,
                float* __restrict__ out,
                float* __restrict__ txx0, float* __restrict__ tzz0, float* __restrict__ txz0,
                float* __restrict__ txx1, float* __restrict__ tzz1, float* __restrict__ txz1) {
    __shared__ float vxl[ROWS + 2][NX_];
    __shared__ float vzl[ROWS + 2][NX_];
    __shared__ float buoy_l[ROWS + 2][NX_];
    __shared__ float lam_l[ROWS][NX_];
    __shared__ float dtmu_l[ROWS][NX_];
    __shared__ float l2m_l[ROWS][NX_];
    __shared__ int rec_r[NREC_];
    __shared__ int rec_zr[NREC_];
    __shared__ int rec_xx[NREC_];
    __shared__ int nrec_loc;

    cg::grid_group grid = cg::this_grid();

    const int tid  = threadIdx.x;
    const int b    = blockIdx.x / TILES;
    const int tile = blockIdx.x % TILES;
    const int z0   = tile * ROWS;
    const int base = b * N_CELL;

    const int sz = src_loc[2 * b];
    const int sx = src_loc[2 * b + 1];

    // ---- one-time setup: materials + zero LDS velocities ----
    for (int idx = tid; idx < (ROWS + 2) * NX_; idx += 256) {
        int zr = idx / NX_;
        int x  = idx - zr * NX_;
        int z  = z0 - 1 + zr;
        vxl[zr][x] = 0.0f;
        vzl[zr][x] = 0.0f;
        if (z >= 0 && z < NZ_) {
            int c = z * NX_ + x;
            float vpi = vp[c], vsi = vs[c], rhoi = rho[c];
            float vs2 = vsi * vsi;
            float mui = rhoi * vs2;
            float lami = rhoi * (vpi * vpi - 2.0f * vs2);
            buoy_l[zr][x] = DT_ / rhoi;
            if (zr >= 1 && zr <= ROWS) {
                lam_l[zr - 1][x]  = lami;
                dtmu_l[zr - 1][x] = DT_ * mui;
                l2m_l[zr - 1][x]  = lami + 2.0f * mui;
            }
        }
    }
    if (tid == 0) {
        int n = 0;
        for (int r = 0; r < NREC_; ++r) {
            int rz = rec_loc[2 * r];
            int rx = rec_loc[2 * r + 1];
            if (rz >= z0 && rz < z0 + ROWS) {
                rec_r[n] = r; rec_zr[n] = rz - z0 + 1; rec_xx[n] = rx; ++n;
            }
        }
        nrec_loc = n;
    }
    __syncthreads();

    for (int t = 0; t < NT_; ++t) {
        const float* txxr = (t & 1) ? txx1 : txx0;
        const float* tzzr = (t & 1) ? tzz1 : tzz0;
        const float* txzr = (t & 1) ? txz1 : txz0;
        float* txxw = (t & 1) ? txx0 : txx1;
        float* tzzw = (t & 1) ? tzz0 : tzz1;
        float* txzw = (t & 1) ? txz0 : txz1;

        // ---- velocity phase: rows z0-1 .. z0+ROWS (halo rows recomputed redundantly;
        // bitwise-identical to the owning block's computation) ----
        for (int idx = tid; idx < (ROWS + 2) * NX_; idx += 256) {
            int zr = idx / NX_;
            int x  = idx - zr * NX_;
            int z  = z0 - 1 + zr;
            if (z < 0 || z >= NZ_) continue;
            int g = base + z * NX_ + x;
            float txx_c = txxr[g];
            float txz_c = txzr[g];
            float dxf_txx = (x < NX_ - 1) ? (txxr[g + 1] - txx_c) / DH_ : 0.0f;
            float dzb_txz = (z >= 1)      ? (txz_c - txzr[g - NX_]) / DH_ : 0.0f;
            float dxb_txz = (x >= 1)      ? (txz_c - txzr[g - 1]) / DH_ : 0.0f;
            float dzf_tzz = (z < NZ_ - 1) ? (tzzr[g + NX_] - tzzr[g]) / DH_ : 0.0f;
            float bu = buoy_l[zr][x];
            vxl[zr][x] = vxl[zr][x] + bu * (dxf_txx + dzb_txz);
            vzl[zr][x] = vzl[zr][x] + bu * (dxb_txz + dzf_tzz);
        }
        __syncthreads();

        // ---- receiver recording (post-velocity snapshot; stress doesn't touch vel) ----
        // out layout: (NT, NREC, 2B) — out[t, r, b]=vx, out[t, r, B+b]=vz
        for (int k = tid; k < nrec_loc; k += 256) {
            size_t o = ((size_t)t * NREC_ + rec_r[k]) * (2 * B_);
            out[o + b]      = vxl[rec_zr[k]][rec_xx[k]];
            out[o + B_ + b] = vzl[rec_zr[k]][rec_xx[k]];
        }

        // ---- stress phase: owned rows only, write to alternate buffer ----
        for (int idx = tid; idx < ROWS * NX_; idx += 256) {
            int zr1 = idx / NX_;          // 0..ROWS-1
            int x   = idx - zr1 * NX_;
            int z   = z0 + zr1;
            int zr  = zr1 + 1;            // LDS vel row
            int g   = base + z * NX_ + x;
            float vx_c = vxl[zr][x];
            float vz_c = vzl[zr][x];
            float dvxdx  = (x >= 1)      ? (vx_c - vxl[zr][x - 1]) / DH_ : 0.0f;
            float dvzdz  = (z >= 1)      ? (vz_c - vzl[zr - 1][x]) / DH_ : 0.0f;
            float dzf_vx = (z < NZ_ - 1) ? (vxl[zr + 1][x] - vx_c) / DH_ : 0.0f;
            float dxf_vz = (x < NX_ - 1) ? (vzl[zr][x + 1] - vz_c) / DH_ : 0.0f;
            float l   = lam_l[zr1][x];
            float l2m = l2m_l[zr1][x];
            float ntxx = txxr[g] + DT_ * (l2m * dvxdx + l * dvzdz);
            float ntzz = tzzr[g] + DT_ * (l * dvxdx + l2m * dvzdz);
            float ntxz = txzr[g] + dtmu_l[zr1][x] * (dzf_vx + dxf_vz);
            if (z == sz && x == sx) {
                float w = wav[b * NT_ + t];
                ntxx = ntxx + w;
                ntzz = ntzz + w;
            }
            txxw[g] = ntxx;
            tzzw[g] = ntzz;
            txzw[g] = ntxz;
        }

        // ---- single grid sync per step: stress(t) visible before vel(t+1) ----
        grid.sync();
    }
}

extern "C" void kernel_launch(void* const* d_in, const int* in_sizes, int n_in,
                              void* d_out, int out_size, void* d_ws, size_t ws_size,
                              hipStream_t stream) {
    const float* xw      = (const float*)d_in[0];   // (B, NT, 1)
    const float* vp      = (const float*)d_in[1];   // (NZ, NX)
    const float* vs      = (const float*)d_in[2];
    const float* rho     = (const float*)d_in[3];
    const int*   src_loc = (const int*)d_in[4];     // (B, 2)
    const int*   rec_loc = (const int*)d_in[5];     // (NREC, 2)
    float*       out     = (float*)d_out;

    float* ws   = (float*)d_ws;
    float* txx0 = ws + 0 * N_FIELD;
    float* tzz0 = ws + 1 * N_FIELD;
    float* txz0 = ws + 2 * N_FIELD;
    float* txx1 = ws + 3 * N_FIELD;
    float* tzz1 = ws + 4 * N_FIELD;
    float* txz1 = ws + 5 * N_FIELD;

    // zero both stress buffers
    hipMemsetAsync(d_ws, 0, (size_t)6 * N_FIELD * sizeof(float), stream);

    void* args[] = { (void*)&vp, (void*)&vs, (void*)&rho, (void*)&xw,
                     (void*)&src_loc, (void*)&rec_loc, (void*)&out,
                     (void*)&txx0, (void*)&tzz0, (void*)&txz0,
                     (void*)&txx1, (void*)&tzz1, (void*)&txz1 };
    hipLaunchCooperativeKernel((void*)wave_persistent, dim3(NBLK), dim3(256),
                               args, 0, stream);
}

// Round 5
// 3795.160 us; speedup vs baseline: 1.4241x; 1.4241x over previous
//
#include <hip/hip_runtime.h>

// Match numpy's rounding exactly: no FMA contraction, same op order as reference.
#pragma clang fp contract(off)

#define B_    4
#define NT_   256
#define NZ_   192
#define NX_   192
#define NREC_ 128
#define DT_   0.001f
#define DH_   10.0f

#define N_CELL  (NZ_ * NX_)        // 36864
#define N_FIELD (B_ * N_CELL)      // 147456

#define K_     4                   // timesteps fused per launch
#define ROWS   8                   // rows owned per block
#define VH     (2 * K_ - 1)        // 7  vel halo rows each side
#define SH     (2 * K_)            // 8  stress halo rows each side
#define VROWS  (ROWS + 2 * VH)     // 22
#define SROWS  (ROWS + 2 * SH)     // 24
#define TILES  (NZ_ / ROWS)        // 24
#define NBLK   (B_ * TILES)        // 96
#define LDS_BYTES ((2 * VROWS + 3 * SROWS) * NX_ * 4)   // 89088

__device__ __forceinline__ int imax_(int a, int b) { return a > b ? a : b; }
__device__ __forceinline__ int imin_(int a, int b) { return a < b ? a : b; }

// ---------------- material precompute ----------------
__global__ void mat_kernel(const float* __restrict__ vp, const float* __restrict__ vs,
                           const float* __restrict__ rho,
                           float* __restrict__ lam, float* __restrict__ dtmu,
                           float* __restrict__ lam2mu, float* __restrict__ buoy) {
    int i = blockIdx.x * blockDim.x + threadIdx.x;
    if (i >= N_CELL) return;
    float vpi = vp[i], vsi = vs[i], rhoi = rho[i];
    float vs2 = vsi * vsi;
    float mui = rhoi * vs2;
    float lami = rhoi * (vpi * vpi - 2.0f * vs2);
    lam[i] = lami;
    dtmu[i] = DT_ * mui;             // reference: DT * mu * (...) == (DT*mu) * (...)
    lam2mu[i] = lami + 2.0f * mui;
    buoy[i] = DT_ / rhoi;
}

// ---------------- K_ fused timesteps with trapezoidal halo recompute ----------------
__global__ void __launch_bounds__(256)
step_kernel(const float* __restrict__ vxr, const float* __restrict__ vzr,
            const float* __restrict__ txxr, const float* __restrict__ tzzr,
            const float* __restrict__ txzr,
            float* __restrict__ vxw, float* __restrict__ vzw,
            float* __restrict__ txxw, float* __restrict__ tzzw, float* __restrict__ txzw,
            const float* __restrict__ lam, const float* __restrict__ dtmu,
            const float* __restrict__ l2m, const float* __restrict__ buoy,
            const float* __restrict__ wav, int t0,
            const int* __restrict__ src_loc, const int* __restrict__ rec_loc,
            float* __restrict__ out) {
    extern __shared__ float smem[];
    float* __restrict__ vxl  = smem;                          // [VROWS][NX_]
    float* __restrict__ vzl  = vxl  + VROWS * NX_;
    float* __restrict__ txxl = vzl  + VROWS * NX_;            // [SROWS][NX_]
    float* __restrict__ tzzl = txxl + SROWS * NX_;
    float* __restrict__ txzl = tzzl + SROWS * NX_;

    const int tid  = threadIdx.x;
    const int b    = blockIdx.x / TILES;
    const int tile = blockIdx.x % TILES;
    const int z0   = tile * ROWS;
    const int base = b * N_CELL;
    const int zv0  = z0 - VH;       // absolute z of vel LDS row 0
    const int zs0  = z0 - SH;       // absolute z of stress LDS row 0

    const int sz = src_loc[2 * b];
    const int sx = src_loc[2 * b + 1];

    // ---- load stress(t0-1) halo region into LDS ----
    for (int idx = tid; idx < SROWS * NX_; idx += 256) {
        int zr = idx / NX_;
        int x  = idx - zr * NX_;
        int z  = zs0 + zr;
        if (z < 0 || z >= NZ_) continue;
        int g = base + z * NX_ + x;
        txxl[idx] = txxr[g];
        tzzl[idx] = tzzr[g];
        txzl[idx] = txzr[g];
    }
    // ---- load vel(t0-1) halo region into LDS ----
    for (int idx = tid; idx < VROWS * NX_; idx += 256) {
        int zr = idx / NX_;
        int x  = idx - zr * NX_;
        int z  = zv0 + zr;
        if (z < 0 || z >= NZ_) continue;
        int g = base + z * NX_ + x;
        vxl[idx] = vxr[g];
        vzl[idx] = vzr[g];
    }
    __syncthreads();

#pragma unroll
    for (int s = 0; s < K_; ++s) {
        const int t = t0 + s;

        // ---- velocity update on rows [z0-hv, z0+ROWS-1+hv] (in-place in LDS) ----
        {
            const int hv  = 2 * (K_ - 1 - s) + 1;
            const int zlo = imax_(0, z0 - hv);
            const int zhi = imin_(NZ_ - 1, z0 + ROWS - 1 + hv);
            const int n   = (zhi - zlo + 1) * NX_;
            for (int idx = tid; idx < n; idx += 256) {
                int dz = idx / NX_;
                int x  = idx - dz * NX_;
                int z  = zlo + dz;
                int zs = (z - zs0) * NX_ + x;    // stress LDS index
                int zr = (z - zv0) * NX_ + x;    // vel LDS index
                float txx_c = txxl[zs];
                float txz_c = txzl[zs];
                float dxf_txx = (x < NX_ - 1) ? (txxl[zs + 1] - txx_c) / DH_ : 0.0f;
                float dzb_txz = (z >= 1)      ? (txz_c - txzl[zs - NX_]) / DH_ : 0.0f;
                float dxb_txz = (x >= 1)      ? (txz_c - txzl[zs - 1]) / DH_ : 0.0f;
                float dzf_tzz = (z < NZ_ - 1) ? (tzzl[zs + NX_] - tzzl[zs]) / DH_ : 0.0f;
                float bu = buoy[z * NX_ + x];
                float nvx = vxl[zr] + bu * (dxf_txx + dzb_txz);
                float nvz = vzl[zr] + bu * (dxb_txz + dzf_tzz);
                vxl[zr] = nvx;
                vzl[zr] = nvz;
                if (s == K_ - 1 && z >= z0 && z < z0 + ROWS) {
                    int g = base + z * NX_ + x;
                    vxw[g] = nvx;
                    vzw[g] = nvz;
                }
            }
        }
        __syncthreads();

        // ---- receiver recording (post-velocity snapshot), owner tile only ----
        // out layout: (NT, NREC, 2B) — out[t, r, b]=vx, out[t, r, B+b]=vz
        if (tid < NREC_) {
            int rz = rec_loc[2 * tid];
            int rx = rec_loc[2 * tid + 1];
            if (rz >= z0 && rz < z0 + ROWS) {
                size_t o = ((size_t)t * NREC_ + tid) * (2 * B_);
                int zr = (rz - zv0) * NX_ + rx;
                out[o + b]      = vxl[zr];
                out[o + B_ + b] = vzl[zr];
            }
        }

        // ---- stress update on rows [z0-hs, z0+ROWS-1+hs] (in-place in LDS) ----
        {
            const int hs  = 2 * (K_ - 1 - s);
            const int zlo = imax_(0, z0 - hs);
            const int zhi = imin_(NZ_ - 1, z0 + ROWS - 1 + hs);
            const int n   = (zhi - zlo + 1) * NX_;
            for (int idx = tid; idx < n; idx += 256) {
                int dz = idx / NX_;
                int x  = idx - dz * NX_;
                int z  = zlo + dz;
                int zs = (z - zs0) * NX_ + x;
                int zr = (z - zv0) * NX_ + x;
                float vx_c = vxl[zr];
                float vz_c = vzl[zr];
                float dvxdx  = (x >= 1)      ? (vx_c - vxl[zr - 1]) / DH_ : 0.0f;
                float dvzdz  = (z >= 1)      ? (vz_c - vzl[zr - NX_]) / DH_ : 0.0f;
                float dzf_vx = (z < NZ_ - 1) ? (vxl[zr + NX_] - vx_c) / DH_ : 0.0f;
                float dxf_vz = (x < NX_ - 1) ? (vzl[zr + 1] - vz_c) / DH_ : 0.0f;
                int c = z * NX_ + x;
                float l  = lam[c];
                float lm = l2m[c];
                float ntxx = txxl[zs] + DT_ * (lm * dvxdx + l * dvzdz);
                float ntzz = tzzl[zs] + DT_ * (l * dvxdx + lm * dvzdz);
                float ntxz = txzl[zs] + dtmu[c] * (dzf_vx + dxf_vz);
                // source injection wherever the recompute range covers it (bit-identical
                // across owner and halo-recomputing blocks)
                if (z == sz && x == sx) {
                    float w = wav[b * NT_ + t];
                    ntxx = ntxx + w;
                    ntzz = ntzz + w;
                }
                txxl[zs] = ntxx;
                tzzl[zs] = ntzz;
                txzl[zs] = ntxz;
                if (s == K_ - 1) {   // computed range == owned range at last substep
                    int g = base + c;
                    txxw[g] = ntxx;
                    tzzw[g] = ntzz;
                    txzw[g] = ntxz;
                }
            }
        }
        __syncthreads();
    }
}

extern "C" void kernel_launch(void* const* d_in, const int* in_sizes, int n_in,
                              void* d_out, int out_size, void* d_ws, size_t ws_size,
                              hipStream_t stream) {
    const float* xw      = (const float*)d_in[0];   // (B, NT, 1)
    const float* vp      = (const float*)d_in[1];   // (NZ, NX)
    const float* vs      = (const float*)d_in[2];
    const float* rho     = (const float*)d_in[3];
    const int*   src_loc = (const int*)d_in[4];     // (B, 2)
    const int*   rec_loc = (const int*)d_in[5];     // (NREC, 2)
    float*       out     = (float*)d_out;

    float* ws = (float*)d_ws;
    // double-buffered wavefields
    float* vx[2]  = { ws + 0 * N_FIELD, ws + 1 * N_FIELD };
    float* vz[2]  = { ws + 2 * N_FIELD, ws + 3 * N_FIELD };
    float* txx[2] = { ws + 4 * N_FIELD, ws + 5 * N_FIELD };
    float* tzz[2] = { ws + 6 * N_FIELD, ws + 7 * N_FIELD };
    float* txz[2] = { ws + 8 * N_FIELD, ws + 9 * N_FIELD };
    float* lam    = ws + 10 * N_FIELD;
    float* dtmu   = lam + N_CELL;
    float* l2m    = dtmu + N_CELL;
    float* buoy   = l2m + N_CELL;

    // zero all wavefield buffers
    hipMemsetAsync(d_ws, 0, (size_t)10 * N_FIELD * sizeof(float), stream);

    mat_kernel<<<(N_CELL + 255) / 256, 256, 0, stream>>>(vp, vs, rho, lam, dtmu, l2m, buoy);

    for (int L = 0; L < NT_ / K_; ++L) {
        int p = L & 1;
        step_kernel<<<NBLK, 256, LDS_BYTES, stream>>>(
            vx[p], vz[p], txx[p], tzz[p], txz[p],
            vx[1 - p], vz[1 - p], txx[1 - p], tzz[1 - p], txz[1 - p],
            lam, dtmu, l2m, buoy,
            xw, L * K_, src_loc, rec_loc, out);
    }
}

// Round 9
// 1253.720 us; speedup vs baseline: 4.3108x; 3.0271x over previous
//
#include <hip/hip_runtime.h>

// Match numpy's rounding exactly: no FMA contraction, same op order as reference.
#pragma clang fp contract(off)

#define B_    4
#define NT_   256
#define NZ_   192
#define NX_   192
#define NREC_ 128
#define DT_   0.001f
#define DH_   10.0f

#define N_CELL  (NZ_ * NX_)        // 36864
#define N_FIELD (B_ * N_CELL)      // 147456

#define K_     4                   // timesteps fused per launch
#define ROWS   4                   // rows owned per block
#define NTHR   1024                // threads per block (16 waves = 4/SIMD)
#define VH     (2 * K_ - 1)        // 7  vel halo rows each side
#define SH     (2 * K_)            // 8  stress halo rows each side
#define VROWS  (ROWS + 2 * VH)     // 18
#define SROWS  (ROWS + 2 * SH)     // 20
#define TILES  (NZ_ / ROWS)        // 48
#define NBLK   (B_ * TILES)        // 192
#define LDS_BYTES ((2 * VROWS + 3 * SROWS) * NX_ * 4)   // 73728

__device__ __forceinline__ int imax_(int a, int b) { return a > b ? a : b; }
__device__ __forceinline__ int imin_(int a, int b) { return a < b ? a : b; }

// ---------------- material precompute ----------------
__global__ void mat_kernel(const float* __restrict__ vp, const float* __restrict__ vs,
                           const float* __restrict__ rho,
                           float* __restrict__ lam, float* __restrict__ dtmu,
                           float* __restrict__ lam2mu, float* __restrict__ buoy) {
    int i = blockIdx.x * blockDim.x + threadIdx.x;
    if (i >= N_CELL) return;
    float vpi = vp[i], vsi = vs[i], rhoi = rho[i];
    float vs2 = vsi * vsi;
    float mui = rhoi * vs2;
    float lami = rhoi * (vpi * vpi - 2.0f * vs2);
    lam[i] = lami;
    dtmu[i] = DT_ * mui;             // reference: DT * mu * (...) == (DT*mu) * (...)
    lam2mu[i] = lami + 2.0f * mui;
    buoy[i] = DT_ / rhoi;
}

// ---------------- K_ fused timesteps with trapezoidal halo recompute ----------------
__global__ void __launch_bounds__(NTHR)
step_kernel(const float* __restrict__ vxr, const float* __restrict__ vzr,
            const float* __restrict__ txxr, const float* __restrict__ tzzr,
            const float* __restrict__ txzr,
            float* __restrict__ vxw, float* __restrict__ vzw,
            float* __restrict__ txxw, float* __restrict__ tzzw, float* __restrict__ txzw,
            const float* __restrict__ lam, const float* __restrict__ dtmu,
            const float* __restrict__ l2m, const float* __restrict__ buoy,
            const float* __restrict__ wav, int t0,
            const int* __restrict__ src_loc, const int* __restrict__ rec_loc,
            float* __restrict__ out) {
    extern __shared__ float smem[];
    float* __restrict__ vxl  = smem;                          // [VROWS][NX_]
    float* __restrict__ vzl  = vxl  + VROWS * NX_;
    float* __restrict__ txxl = vzl  + VROWS * NX_;            // [SROWS][NX_]
    float* __restrict__ tzzl = txxl + SROWS * NX_;
    float* __restrict__ txzl = tzzl + SROWS * NX_;

    const int tid  = threadIdx.x;
    const int b    = blockIdx.x / TILES;
    const int tile = blockIdx.x % TILES;
    const int z0   = tile * ROWS;
    const int base = b * N_CELL;
    const int zv0  = z0 - VH;       // absolute z of vel LDS row 0
    const int zs0  = z0 - SH;       // absolute z of stress LDS row 0

    const int sz = src_loc[2 * b];
    const int sx = src_loc[2 * b + 1];

    // ---- load stress(t0-1) halo region into LDS ----
    for (int idx = tid; idx < SROWS * NX_; idx += NTHR) {
        int zr = idx / NX_;
        int x  = idx - zr * NX_;
        int z  = zs0 + zr;
        if (z < 0 || z >= NZ_) continue;
        int g = base + z * NX_ + x;
        txxl[idx] = txxr[g];
        tzzl[idx] = tzzr[g];
        txzl[idx] = txzr[g];
    }
    // ---- load vel(t0-1) halo region into LDS ----
    for (int idx = tid; idx < VROWS * NX_; idx += NTHR) {
        int zr = idx / NX_;
        int x  = idx - zr * NX_;
        int z  = zv0 + zr;
        if (z < 0 || z >= NZ_) continue;
        int g = base + z * NX_ + x;
        vxl[idx] = vxr[g];
        vzl[idx] = vzr[g];
    }
    __syncthreads();

#pragma unroll
    for (int s = 0; s < K_; ++s) {
        const int t = t0 + s;

        // ---- velocity update on rows [z0-hv, z0+ROWS-1+hv] (in-place in LDS) ----
        {
            const int hv  = 2 * (K_ - 1 - s) + 1;
            const int zlo = imax_(0, z0 - hv);
            const int zhi = imin_(NZ_ - 1, z0 + ROWS - 1 + hv);
            const int n   = (zhi - zlo + 1) * NX_;
            for (int idx = tid; idx < n; idx += NTHR) {
                int dz = idx / NX_;
                int x  = idx - dz * NX_;
                int z  = zlo + dz;
                int zs = (z - zs0) * NX_ + x;    // stress LDS index
                int zr = (z - zv0) * NX_ + x;    // vel LDS index
                float txx_c = txxl[zs];
                float txz_c = txzl[zs];
                float dxf_txx = (x < NX_ - 1) ? (txxl[zs + 1] - txx_c) / DH_ : 0.0f;
                float dzb_txz = (z >= 1)      ? (txz_c - txzl[zs - NX_]) / DH_ : 0.0f;
                float dxb_txz = (x >= 1)      ? (txz_c - txzl[zs - 1]) / DH_ : 0.0f;
                float dzf_tzz = (z < NZ_ - 1) ? (tzzl[zs + NX_] - tzzl[zs]) / DH_ : 0.0f;
                float bu = buoy[z * NX_ + x];
                float nvx = vxl[zr] + bu * (dxf_txx + dzb_txz);
                float nvz = vzl[zr] + bu * (dxb_txz + dzf_tzz);
                vxl[zr] = nvx;
                vzl[zr] = nvz;
                if (s == K_ - 1 && z >= z0 && z < z0 + ROWS) {
                    int g = base + z * NX_ + x;
                    vxw[g] = nvx;
                    vzw[g] = nvz;
                }
            }
        }
        __syncthreads();

        // ---- receiver recording (post-velocity snapshot), owner tile only ----
        // out layout: (NT, NREC, 2B) — out[t, r, b]=vx, out[t, r, B+b]=vz
        if (tid < NREC_) {
            int rz = rec_loc[2 * tid];
            int rx = rec_loc[2 * tid + 1];
            if (rz >= z0 && rz < z0 + ROWS) {
                size_t o = ((size_t)t * NREC_ + tid) * (2 * B_);
                int zr = (rz - zv0) * NX_ + rx;
                out[o + b]      = vxl[zr];
                out[o + B_ + b] = vzl[zr];
            }
        }

        // ---- stress update on rows [z0-hs, z0+ROWS-1+hs] (in-place in LDS) ----
        {
            const int hs  = 2 * (K_ - 1 - s);
            const int zlo = imax_(0, z0 - hs);
            const int zhi = imin_(NZ_ - 1, z0 + ROWS - 1 + hs);
            const int n   = (zhi - zlo + 1) * NX_;
            for (int idx = tid; idx < n; idx += NTHR) {
                int dz = idx / NX_;
                int x  = idx - dz * NX_;
                int z  = zlo + dz;
                int zs = (z - zs0) * NX_ + x;
                int zr = (z - zv0) * NX_ + x;
                float vx_c = vxl[zr];
                float vz_c = vzl[zr];
                float dvxdx  = (x >= 1)      ? (vx_c - vxl[zr - 1]) / DH_ : 0.0f;
                float dvzdz  = (z >= 1)      ? (vz_c - vzl[zr - NX_]) / DH_ : 0.0f;
                float dzf_vx = (z < NZ_ - 1) ? (vxl[zr + NX_] - vx_c) / DH_ : 0.0f;
                float dxf_vz = (x < NX_ - 1) ? (vzl[zr + 1] - vz_c) / DH_ : 0.0f;
                int c = z * NX_ + x;
                float l  = lam[c];
                float lm = l2m[c];
                float ntxx = txxl[zs] + DT_ * (lm * dvxdx + l * dvzdz);
                float ntzz = tzzl[zs] + DT_ * (l * dvxdx + lm * dvzdz);
                float ntxz = txzl[zs] + dtmu[c] * (dzf_vx + dxf_vz);
                // source injection wherever the recompute range covers it (bit-identical
                // across owner and halo-recomputing blocks)
                if (z == sz && x == sx) {
                    float w = wav[b * NT_ + t];
                    ntxx = ntxx + w;
                    ntzz = ntzz + w;
                }
                txxl[zs] = ntxx;
                tzzl[zs] = ntzz;
                txzl[zs] = ntxz;
                if (s == K_ - 1) {   // computed range == owned range at last substep
                    int g = base + c;
                    txxw[g] = ntxx;
                    tzzw[g] = ntzz;
                    txzw[g] = ntxz;
                }
            }
        }
        __syncthreads();
    }
}

extern "C" void kernel_launch(void* const* d_in, const int* in_sizes, int n_in,
                              void* d_out, int out_size, void* d_ws, size_t ws_size,
                              hipStream_t stream) {
    const float* xw      = (const float*)d_in[0];   // (B, NT, 1)
    const float* vp      = (const float*)d_in[1];   // (NZ, NX)
    const float* vs      = (const float*)d_in[2];
    const float* rho     = (const float*)d_in[3];
    const int*   src_loc = (const int*)d_in[4];     // (B, 2)
    const int*   rec_loc = (const int*)d_in[5];     // (NREC, 2)
    float*       out     = (float*)d_out;

    float* ws = (float*)d_ws;
    // double-buffered wavefields
    float* vx[2]  = { ws + 0 * N_FIELD, ws + 1 * N_FIELD };
    float* vz[2]  = { ws + 2 * N_FIELD, ws + 3 * N_FIELD };
    float* txx[2] = { ws + 4 * N_FIELD, ws + 5 * N_FIELD };
    float* tzz[2] = { ws + 6 * N_FIELD, ws + 7 * N_FIELD };
    float* txz[2] = { ws + 8 * N_FIELD, ws + 9 * N_FIELD };
    float* lam    = ws + 10 * N_FIELD;
    float* dtmu   = lam + N_CELL;
    float* l2m    = dtmu + N_CELL;
    float* buoy   = l2m + N_CELL;

    // zero all wavefield buffers
    hipMemsetAsync(d_ws, 0, (size_t)10 * N_FIELD * sizeof(float), stream);

    mat_kernel<<<(N_CELL + 255) / 256, 256, 0, stream>>>(vp, vs, rho, lam, dtmu, l2m, buoy);

    for (int L = 0; L < NT_ / K_; ++L) {
        int p = L & 1;
        step_kernel<<<NBLK, NTHR, LDS_BYTES, stream>>>(
            vx[p], vz[p], txx[p], tzz[p], txz[p],
            vx[1 - p], vz[1 - p], txx[1 - p], tzz[1 - p], txz[1 - p],
            lam, dtmu, l2m, buoy,
            xw, L * K_, src_loc, rec_loc, out);
    }
}

// Round 10
// 1193.271 us; speedup vs baseline: 4.5292x; 1.0507x over previous
//
#include <hip/hip_runtime.h>

// Match numpy's rounding exactly: no FMA contraction, same op order as reference.
#pragma clang fp contract(off)

#define B_    4
#define NT_   256
#define NZ_   192
#define NX_   192
#define NREC_ 128
#define DT_   0.001f
#define DH_   10.0f

#define N_CELL  (NZ_ * NX_)        // 36864
#define N_FIELD (B_ * N_CELL)      // 147456

#define K_     4                   // timesteps fused per launch
#define ROWS   4                   // rows owned per block
#define NTHR   1024                // threads per block (16 waves = 4/SIMD)
#define VH     (2 * K_ - 1)        // 7  vel halo rows each side
#define SH     (2 * K_)            // 8  stress halo rows each side
#define VROWS  (ROWS + 2 * VH)     // 18
#define SROWS  (ROWS + 2 * SH)     // 20
#define TILES  (NZ_ / ROWS)        // 48
#define NBLK   (B_ * TILES)        // 192
#define LDS_BYTES ((2 * VROWS + 3 * SROWS) * NX_ * 4)   // 73728

__device__ __forceinline__ int imax_(int a, int b) { return a > b ? a : b; }
__device__ __forceinline__ int imin_(int a, int b) { return a < b ? a : b; }

// ---------------- material precompute ----------------
__global__ void mat_kernel(const float* __restrict__ vp, const float* __restrict__ vs,
                           const float* __restrict__ rho,
                           float* __restrict__ lam, float* __restrict__ dtmu,
                           float* __restrict__ lam2mu, float* __restrict__ buoy) {
    int i = blockIdx.x * blockDim.x + threadIdx.x;
    if (i >= N_CELL) return;
    float vpi = vp[i], vsi = vs[i], rhoi = rho[i];
    float vs2 = vsi * vsi;
    float mui = rhoi * vs2;
    float lami = rhoi * (vpi * vpi - 2.0f * vs2);
    lam[i] = lami;
    dtmu[i] = DT_ * mui;             // reference: DT * mu * (...) == (DT*mu) * (...)
    lam2mu[i] = lami + 2.0f * mui;
    buoy[i] = DT_ / rhoi;
}

// One fused substep with compile-time S: trip counts are constants -> full unroll,
// all LDS reads of a phase issue before one waitcnt (ILP hides ds_read latency).
template<int S>
__device__ __forceinline__ void substep(
    int tid, int z0, int base, int zv0, int zs0, int sz, int sx, int b, int t0,
    float* __restrict__ vxl, float* __restrict__ vzl,
    float* __restrict__ txxl, float* __restrict__ tzzl, float* __restrict__ txzl,
    const float* __restrict__ lam, const float* __restrict__ dtmu,
    const float* __restrict__ l2m, const float* __restrict__ buoy,
    const float* __restrict__ wav,
    bool rec_ok, int rec_idx, float* __restrict__ out,
    float* __restrict__ vxw, float* __restrict__ vzw,
    float* __restrict__ txxw, float* __restrict__ tzzw, float* __restrict__ txzw) {
    const int t = t0 + S;

    // ---- velocity update on rows [z0-hv, z0+ROWS-1+hv] (in-place in LDS) ----
    {
        constexpr int hv = 2 * (K_ - 1 - S) + 1;
        constexpr int IV = ((ROWS + 2 * hv) * NX_ + NTHR - 1) / NTHR;
        const int zlo = imax_(0, z0 - hv);
        const int zhi = imin_(NZ_ - 1, z0 + ROWS - 1 + hv);
        const int n   = (zhi - zlo + 1) * NX_;
#pragma unroll
        for (int it = 0; it < IV; ++it) {
            int idx = tid + it * NTHR;
            if (idx < n) {
                int dz = idx / NX_;
                int x  = idx - dz * NX_;
                int z  = zlo + dz;
                int zs = (z - zs0) * NX_ + x;    // stress LDS index
                int zr = (z - zv0) * NX_ + x;    // vel LDS index
                float txx_c = txxl[zs];
                float txz_c = txzl[zs];
                float dxf_txx = (x < NX_ - 1) ? (txxl[zs + 1] - txx_c) / DH_ : 0.0f;
                float dzb_txz = (z >= 1)      ? (txz_c - txzl[zs - NX_]) / DH_ : 0.0f;
                float dxb_txz = (x >= 1)      ? (txz_c - txzl[zs - 1]) / DH_ : 0.0f;
                float dzf_tzz = (z < NZ_ - 1) ? (tzzl[zs + NX_] - tzzl[zs]) / DH_ : 0.0f;
                float bu = buoy[z * NX_ + x];
                float nvx = vxl[zr] + bu * (dxf_txx + dzb_txz);
                float nvz = vzl[zr] + bu * (dxb_txz + dzf_tzz);
                vxl[zr] = nvx;
                vzl[zr] = nvz;
                if (S == K_ - 1) {
                    if (z >= z0 && z < z0 + ROWS) {
                        int g = base + z * NX_ + x;
                        vxw[g] = nvx;
                        vzw[g] = nvz;
                    }
                }
            }
        }
    }
    __syncthreads();

    // ---- receiver recording (post-velocity snapshot), owner tile only ----
    // out layout: (NT, NREC, 2B) — out[t, r, b]=vx, out[t, r, B+b]=vz
    if (rec_ok) {
        size_t o = ((size_t)t * NREC_ + tid) * (2 * B_);
        out[o + b]      = vxl[rec_idx];
        out[o + B_ + b] = vzl[rec_idx];
    }

    // ---- stress update on rows [z0-hs, z0+ROWS-1+hs] (in-place in LDS) ----
    {
        constexpr int hs = 2 * (K_ - 1 - S);
        constexpr int IS = ((ROWS + 2 * hs) * NX_ + NTHR - 1) / NTHR;
        const int zlo = imax_(0, z0 - hs);
        const int zhi = imin_(NZ_ - 1, z0 + ROWS - 1 + hs);
        const int n   = (zhi - zlo + 1) * NX_;
#pragma unroll
        for (int it = 0; it < IS; ++it) {
            int idx = tid + it * NTHR;
            if (idx < n) {
                int dz = idx / NX_;
                int x  = idx - dz * NX_;
                int z  = zlo + dz;
                int zs = (z - zs0) * NX_ + x;
                int zr = (z - zv0) * NX_ + x;
                float vx_c = vxl[zr];
                float vz_c = vzl[zr];
                float dvxdx  = (x >= 1)      ? (vx_c - vxl[zr - 1]) / DH_ : 0.0f;
                float dvzdz  = (z >= 1)      ? (vz_c - vzl[zr - NX_]) / DH_ : 0.0f;
                float dzf_vx = (z < NZ_ - 1) ? (vxl[zr + NX_] - vx_c) / DH_ : 0.0f;
                float dxf_vz = (x < NX_ - 1) ? (vzl[zr + 1] - vz_c) / DH_ : 0.0f;
                int c = z * NX_ + x;
                float l  = lam[c];
                float lm = l2m[c];
                float ntxx = txxl[zs] + DT_ * (lm * dvxdx + l * dvzdz);
                float ntzz = tzzl[zs] + DT_ * (l * dvxdx + lm * dvzdz);
                float ntxz = txzl[zs] + dtmu[c] * (dzf_vx + dxf_vz);
                // source injection wherever the recompute range covers it (bit-identical
                // across owner and halo-recomputing blocks)
                if (z == sz && x == sx) {
                    float w = wav[b * NT_ + t];
                    ntxx = ntxx + w;
                    ntzz = ntzz + w;
                }
                txxl[zs] = ntxx;
                tzzl[zs] = ntzz;
                txzl[zs] = ntxz;
                if (S == K_ - 1) {   // computed range == owned range at last substep
                    int g = base + c;
                    txxw[g] = ntxx;
                    tzzw[g] = ntzz;
                    txzw[g] = ntxz;
                }
            }
        }
    }
    __syncthreads();
}

// ---------------- K_ fused timesteps with trapezoidal halo recompute ----------------
__global__ void __launch_bounds__(NTHR, 4)
step_kernel(const float* __restrict__ vxr, const float* __restrict__ vzr,
            const float* __restrict__ txxr, const float* __restrict__ tzzr,
            const float* __restrict__ txzr,
            float* __restrict__ vxw, float* __restrict__ vzw,
            float* __restrict__ txxw, float* __restrict__ tzzw, float* __restrict__ txzw,
            const float* __restrict__ lam, const float* __restrict__ dtmu,
            const float* __restrict__ l2m, const float* __restrict__ buoy,
            const float* __restrict__ wav, int t0,
            const int* __restrict__ src_loc, const int* __restrict__ rec_loc,
            float* __restrict__ out) {
    extern __shared__ float smem[];
    float* __restrict__ vxl  = smem;                          // [VROWS][NX_]
    float* __restrict__ vzl  = vxl  + VROWS * NX_;
    float* __restrict__ txxl = vzl  + VROWS * NX_;            // [SROWS][NX_]
    float* __restrict__ tzzl = txxl + SROWS * NX_;
    float* __restrict__ txzl = tzzl + SROWS * NX_;

    const int tid  = threadIdx.x;
    const int b    = blockIdx.x / TILES;
    const int tile = blockIdx.x % TILES;
    const int z0   = tile * ROWS;
    const int base = b * N_CELL;
    const int zv0  = z0 - VH;       // absolute z of vel LDS row 0
    const int zs0  = z0 - SH;       // absolute z of stress LDS row 0

    const int sz = src_loc[2 * b];
    const int sx = src_loc[2 * b + 1];

    // receiver assignment hoisted out of the time loop
    bool rec_ok = false;
    int rec_idx = 0;
    if (tid < NREC_) {
        int rz = rec_loc[2 * tid];
        int rx = rec_loc[2 * tid + 1];
        if (rz >= z0 && rz < z0 + ROWS) {
            rec_ok = true;
            rec_idx = (rz - zv0) * NX_ + rx;
        }
    }

    // ---- load stress(t0-1) halo region into LDS ----
#pragma unroll
    for (int idx = tid; idx < SROWS * NX_; idx += NTHR) {
        int zr = idx / NX_;
        int x  = idx - zr * NX_;
        int z  = zs0 + zr;
        if (z < 0 || z >= NZ_) continue;
        int g = base + z * NX_ + x;
        txxl[idx] = txxr[g];
        tzzl[idx] = tzzr[g];
        txzl[idx] = txzr[g];
    }
    // ---- load vel(t0-1) halo region into LDS ----
#pragma unroll
    for (int idx = tid; idx < VROWS * NX_; idx += NTHR) {
        int zr = idx / NX_;
        int x  = idx - zr * NX_;
        int z  = zv0 + zr;
        if (z < 0 || z >= NZ_) continue;
        int g = base + z * NX_ + x;
        vxl[idx] = vxr[g];
        vzl[idx] = vzr[g];
    }
    __syncthreads();

    substep<0>(tid, z0, base, zv0, zs0, sz, sx, b, t0, vxl, vzl, txxl, tzzl, txzl,
               lam, dtmu, l2m, buoy, wav, rec_ok, rec_idx, out, vxw, vzw, txxw, tzzw, txzw);
    substep<1>(tid, z0, base, zv0, zs0, sz, sx, b, t0, vxl, vzl, txxl, tzzl, txzl,
               lam, dtmu, l2m, buoy, wav, rec_ok, rec_idx, out, vxw, vzw, txxw, tzzw, txzw);
    substep<2>(tid, z0, base, zv0, zs0, sz, sx, b, t0, vxl, vzl, txxl, tzzl, txzl,
               lam, dtmu, l2m, buoy, wav, rec_ok, rec_idx, out, vxw, vzw, txxw, tzzw, txzw);
    substep<3>(tid, z0, base, zv0, zs0, sz, sx, b, t0, vxl, vzl, txxl, tzzl, txzl,
               lam, dtmu, l2m, buoy, wav, rec_ok, rec_idx, out, vxw, vzw, txxw, tzzw, txzw);
}

extern "C" void kernel_launch(void* const* d_in, const int* in_sizes, int n_in,
                              void* d_out, int out_size, void* d_ws, size_t ws_size,
                              hipStream_t stream) {
    const float* xw      = (const float*)d_in[0];   // (B, NT, 1)
    const float* vp      = (const float*)d_in[1];   // (NZ, NX)
    const float* vs      = (const float*)d_in[2];
    const float* rho     = (const float*)d_in[3];
    const int*   src_loc = (const int*)d_in[4];     // (B, 2)
    const int*   rec_loc = (const int*)d_in[5];     // (NREC, 2)
    float*       out     = (float*)d_out;

    float* ws = (float*)d_ws;
    // double-buffered wavefields
    float* vx[2]  = { ws + 0 * N_FIELD, ws + 1 * N_FIELD };
    float* vz[2]  = { ws + 2 * N_FIELD, ws + 3 * N_FIELD };
    float* txx[2] = { ws + 4 * N_FIELD, ws + 5 * N_FIELD };
    float* tzz[2] = { ws + 6 * N_FIELD, ws + 7 * N_FIELD };
    float* txz[2] = { ws + 8 * N_FIELD, ws + 9 * N_FIELD };
    float* lam    = ws + 10 * N_FIELD;
    float* dtmu   = lam + N_CELL;
    float* l2m    = dtmu + N_CELL;
    float* buoy   = l2m + N_CELL;

    // zero all wavefield buffers
    hipMemsetAsync(d_ws, 0, (size_t)10 * N_FIELD * sizeof(float), stream);

    mat_kernel<<<(N_CELL + 255) / 256, 256, 0, stream>>>(vp, vs, rho, lam, dtmu, l2m, buoy);

    for (int L = 0; L < NT_ / K_; ++L) {
        int p = L & 1;
        step_kernel<<<NBLK, NTHR, LDS_BYTES, stream>>>(
            vx[p], vz[p], txx[p], tzz[p], txz[p],
            vx[1 - p], vz[1 - p], txx[1 - p], tzz[1 - p], txz[1 - p],
            lam, dtmu, l2m, buoy,
            xw, L * K_, src_loc, rec_loc, out);
    }
}